// Round 6
// baseline (77.536 us; speedup 1.0000x reference)
//
#include <hip/hip_runtime.h>

// LeakageNlinCore as fused GEMM: out[pos,:] = M(W) · f(x[pos,:]),
//   f[k] = k<64 ? amp_k*xr_k : amp_{k-64}*xi_{k-64},  amp = xr^2+xi^2
//   M row n (=2c+o): W[c,o,:126] scattered over cols != c (2x2 zero diag).
//
// Round 6: MEASUREMENT ROUND. Round-5 post-mortem: build-cost theory dead
// (2.5x less build VALU, half the builds -> only -2.2us). Kernel has been
// invisible in rocprof top-5 since round 2 (beaten by 45us/268MB harness
// poison fills) -> no counters, and two contradictory timing models
// (floor~50/k~20 vs floor~30/k~42). This round repeats the compute R=3
// times inside the kernel (idempotent: same stages, same stores) to push
// the dispatch above 45us so it surfaces in top-5 WITH counters, and to
// split dur_us into floor + k_cold + 2*k_warm. Structure otherwise
// byte-identical to round 5.

typedef _Float16 f16x8 __attribute__((ext_vector_type(8)));
typedef _Float16 f16x2 __attribute__((ext_vector_type(2)));
typedef float    floatx4 __attribute__((ext_vector_type(4)));

#define NPOS  32768             // B*S
#define CPOS  64                // positions per chunk
#define NCH   2                 // chunks per block
#define BPOS  (CPOS * NCH)      // 128 positions per block
#define NBLK  (NPOS / BPOS)     // 256 blocks
#define NTHR  512               // 8 waves
#define NREP  3                 // internal repeats (measurement)
#define MS    136               // padded LDS row stride in f16 (272B; 68 dw
                                // = 4 mod 32 -> balanced banks, 16B aligned)

__global__ __launch_bounds__(NTHR, 2)
void leakage_kernel_r3(const float* __restrict__ x,
                       const float* __restrict__ W,
                       float* __restrict__ out) {
    __shared__ __align__(16) _Float16 Mt[128][MS];   // M (f16): [row n][col k]
    __shared__ __align__(16) _Float16 fsh[CPOS][MS]; // f (f16): [pos][k]

    const int tid  = threadIdx.x;
    const int w    = tid >> 6;        // wave 0..7 -> n-tile w
    const int lane = tid & 63;
    const int q    = lane >> 4, r = lane & 15;

    // ---- Build M from W: division-free, coalesced float2 reads ------------
    const float2* __restrict__ W2 = (const float2*)W;
#pragma unroll
    for (int it = 0; it < 16; ++it) {
        const int e  = tid + NTHR * it;      // < 8192
        const int n  = e >> 6;
        const int m2 = e & 63;
        if (m2 < 63) {
            const int c = n >> 1;
            const float2 v = W2[n * 63 + m2];
#pragma unroll
            for (int u = 0; u < 2; ++u) {
                const int m    = 2 * m2 + u;
                const int half = (m >= 63) ? 1 : 0;
                const int mh   = m - 63 * half;
                const int k    = 64 * half + mh + (mh >= c ? 1 : 0);
                Mt[n][k] = (_Float16)(u == 0 ? v.x : v.y);
            }
        }
    }
    if (tid < 128) {
        const int c = tid >> 1;
        Mt[tid][c]      = (_Float16)0.f;
        Mt[tid][64 + c] = (_Float16)0.f;
    }
    __syncthreads();

    // ---- B fragments: wave w owns n-tile w (cols n = 16w..16w+15) ---------
    f16x8 B0 = *(const f16x8*)&Mt[16 * w + r][ 0 + 8 * q];
    f16x8 B1 = *(const f16x8*)&Mt[16 * w + r][32 + 8 * q];
    f16x8 B2 = *(const f16x8*)&Mt[16 * w + r][64 + 8 * q];
    f16x8 B3 = *(const f16x8*)&Mt[16 * w + r][96 + 8 * q];

    const int pblk = blockIdx.x * BPOS;

#pragma unroll 1
    for (int rep = 0; rep < NREP; ++rep) {
#pragma unroll 1
        for (int ch = 0; ch < NCH; ++ch) {
            // ---- Stage chunk ch into fsh (coalesced float4 x reads) -------
            __syncthreads();   // prior readers of fsh done
            {
                const float4* __restrict__ x4 =
                    (const float4*)x + (size_t)(pblk + ch * CPOS) * 32;
#pragma unroll
                for (int it = 0; it < 4; ++it) {
                    const int g = tid + NTHR * it;   // float4 idx, < 2048
                    const int p = g >> 5;            // local pos 0..63
                    const int i = g & 31;            // channel pair (2i, 2i+1)
                    const float4 v = x4[g];          // (xr0, xi0, xr1, xi1)
                    const float a0 = v.x * v.x + v.y * v.y;
                    const float a1 = v.z * v.z + v.w * v.w;
                    *(f16x2*)&fsh[p][2 * i] =
                        f16x2{ (_Float16)(a0 * v.x), (_Float16)(a1 * v.z) };
                    *(f16x2*)&fsh[p][64 + 2 * i] =
                        f16x2{ (_Float16)(a0 * v.y), (_Float16)(a1 * v.w) };
                }
            }
            __syncthreads();

            // ---- Compute chunk ch: 4 pos-tiles x (4 A-reads + 4 MFMA) -----
#pragma unroll
            for (int pt = 0; pt < 4; ++pt) {
                const int pr = pt * 16 + r;      // A operand: m = lane&15
                f16x8 A0 = *(const f16x8*)&fsh[pr][ 0 + 8 * q];
                f16x8 A1 = *(const f16x8*)&fsh[pr][32 + 8 * q];
                f16x8 A2 = *(const f16x8*)&fsh[pr][64 + 8 * q];
                f16x8 A3 = *(const f16x8*)&fsh[pr][96 + 8 * q];

                floatx4 C = {0.f, 0.f, 0.f, 0.f};
                C = __builtin_amdgcn_mfma_f32_16x16x32_f16(A0, B0, C, 0, 0, 0);
                C = __builtin_amdgcn_mfma_f32_16x16x32_f16(A1, B1, C, 0, 0, 0);
                C = __builtin_amdgcn_mfma_f32_16x16x32_f16(A2, B2, C, 0, 0, 0);
                C = __builtin_amdgcn_mfma_f32_16x16x32_f16(A3, B3, C, 0, 0, 0);

                // C layout (16x16): col = r (n), row = 4q+reg (m = pos).
                float* __restrict__ op =
                    out + (size_t)(pblk + ch * CPOS + pt * 16) * 128;
#pragma unroll
                for (int reg = 0; reg < 4; ++reg) {
                    op[(size_t)(4 * q + reg) * 128 + 16 * w + r] = C[reg];
                }
            }
        }
    }
}

extern "C" void kernel_launch(void* const* d_in, const int* in_sizes, int n_in,
                              void* d_out, int out_size, void* d_ws, size_t ws_size,
                              hipStream_t stream) {
    const float* x = (const float*)d_in[0];   // [4,8192,64,2] fp32
    const float* W = (const float*)d_in[1];   // [64,2,126]    fp32
    float* out = (float*)d_out;               // [4,8192,64,2] fp32

    hipLaunchKernelGGL(leakage_kernel_r3, dim3(NBLK), dim3(NTHR), 0, stream,
                       x, W, out);
}

// Round 7
// 71.010 us; speedup vs baseline: 1.0919x; 1.0919x over previous
//
#include <hip/hip_runtime.h>

// LeakageNlinCore as fused GEMM: out[pos,:] = M(W) · f(x[pos,:]),
//   f[k] = k<64 ? amp_k*xr_k : amp_{k-64}*xi_{k-64},  amp = xr^2+xi^2
//   M row n (=2c+o): W[c,o,:126] scattered over cols != c (2x2 zero diag).
//
// Round 7 (round-6 measurement: warm rep = 2.65us — compute engine-room is
// near-free; dur_us carries a ~55-65us harness floor; only suspect left in
// the cold rep is exposed HBM latency from phase serialization at 1
// block/CU). Software-pipelined version of round 5:
//   - chunk-0 x loads issued BEFORE the M-build VALU (latency behind build)
//   - chunk-1 x loads issued BEFORE chunk-0 MFMAs (latency behind compute)
//   - fsh double-buffered (69 KB LDS total) -> no barrier between compute-0
//     and stage-1; one barrier per chunk instead of two.

typedef _Float16 f16x8 __attribute__((ext_vector_type(8)));
typedef _Float16 f16x2 __attribute__((ext_vector_type(2)));
typedef float    floatx4 __attribute__((ext_vector_type(4)));

#define NPOS  32768             // B*S
#define CPOS  64                // positions per chunk
#define BPOS  (CPOS * 2)        // 128 positions per block (2 chunks)
#define NBLK  (NPOS / BPOS)     // 256 blocks
#define NTHR  512               // 8 waves
#define MS    136               // padded LDS row stride in f16 (272B; 68 dw
                                // = 4 mod 32 -> balanced banks, 16B aligned)

__global__ __launch_bounds__(NTHR, 2)
void leakage_kernel_pipe(const float* __restrict__ x,
                         const float* __restrict__ W,
                         float* __restrict__ out) {
    __shared__ __align__(16) _Float16 Mt[128][MS];       // M (f16)
    __shared__ __align__(16) _Float16 fsh[2][CPOS][MS];  // f (f16), dbuf

    const int tid  = threadIdx.x;
    const int w    = tid >> 6;        // wave 0..7 -> n-tile w
    const int lane = tid & 63;
    const int q    = lane >> 4, r = lane & 15;

    const int pblk = blockIdx.x * BPOS;
    const float4* __restrict__ x4 = (const float4*)x + (size_t)pblk * 32;

    // ---- Issue chunk-0 x loads FIRST (fly behind the M-build VALU) --------
    float4 v0[4];
#pragma unroll
    for (int it = 0; it < 4; ++it) v0[it] = x4[tid + NTHR * it];

    // ---- Build M from W: division-free, coalesced float2 reads ------------
    const float2* __restrict__ W2 = (const float2*)W;
#pragma unroll
    for (int it = 0; it < 16; ++it) {
        const int e  = tid + NTHR * it;      // < 8192
        const int n  = e >> 6;
        const int m2 = e & 63;
        if (m2 < 63) {
            const int c = n >> 1;
            const float2 v = W2[n * 63 + m2];
#pragma unroll
            for (int u = 0; u < 2; ++u) {
                const int m    = 2 * m2 + u;
                const int half = (m >= 63) ? 1 : 0;
                const int mh   = m - 63 * half;
                const int k    = 64 * half + mh + (mh >= c ? 1 : 0);
                Mt[n][k] = (_Float16)(u == 0 ? v.x : v.y);
            }
        }
    }
    if (tid < 128) {
        const int c = tid >> 1;
        Mt[tid][c]      = (_Float16)0.f;
        Mt[tid][64 + c] = (_Float16)0.f;
    }

    // ---- Stage chunk 0 into fsh[0] ----------------------------------------
#pragma unroll
    for (int it = 0; it < 4; ++it) {
        const int g = tid + NTHR * it;       // float4 idx, < 2048
        const int p = g >> 5;                // local pos 0..63
        const int i = g & 31;                // channel pair (2i, 2i+1)
        const float4 v = v0[it];             // (xr0, xi0, xr1, xi1)
        const float a0 = v.x * v.x + v.y * v.y;
        const float a1 = v.z * v.z + v.w * v.w;
        *(f16x2*)&fsh[0][p][2 * i] =
            f16x2{ (_Float16)(a0 * v.x), (_Float16)(a1 * v.z) };
        *(f16x2*)&fsh[0][p][64 + 2 * i] =
            f16x2{ (_Float16)(a0 * v.y), (_Float16)(a1 * v.w) };
    }
    __syncthreads();

    // ---- B fragments: wave w owns n-tile w (cols n = 16w..16w+15) ---------
    f16x8 B0 = *(const f16x8*)&Mt[16 * w + r][ 0 + 8 * q];
    f16x8 B1 = *(const f16x8*)&Mt[16 * w + r][32 + 8 * q];
    f16x8 B2 = *(const f16x8*)&Mt[16 * w + r][64 + 8 * q];
    f16x8 B3 = *(const f16x8*)&Mt[16 * w + r][96 + 8 * q];

    // ---- Issue chunk-1 x loads (fly behind chunk-0 MFMAs) -----------------
    float4 v1[4];
#pragma unroll
    for (int it = 0; it < 4; ++it) v1[it] = x4[2048 + tid + NTHR * it];

    // ---- Compute chunk 0: 4 pos-tiles x (4 A-reads + 4 MFMA) + stores -----
#pragma unroll
    for (int pt = 0; pt < 4; ++pt) {
        const int pr = pt * 16 + r;          // A operand: m = lane&15 = pos
        f16x8 A0 = *(const f16x8*)&fsh[0][pr][ 0 + 8 * q];
        f16x8 A1 = *(const f16x8*)&fsh[0][pr][32 + 8 * q];
        f16x8 A2 = *(const f16x8*)&fsh[0][pr][64 + 8 * q];
        f16x8 A3 = *(const f16x8*)&fsh[0][pr][96 + 8 * q];

        floatx4 C = {0.f, 0.f, 0.f, 0.f};
        C = __builtin_amdgcn_mfma_f32_16x16x32_f16(A0, B0, C, 0, 0, 0);
        C = __builtin_amdgcn_mfma_f32_16x16x32_f16(A1, B1, C, 0, 0, 0);
        C = __builtin_amdgcn_mfma_f32_16x16x32_f16(A2, B2, C, 0, 0, 0);
        C = __builtin_amdgcn_mfma_f32_16x16x32_f16(A3, B3, C, 0, 0, 0);

        // C layout (16x16): col = r (n), row = 4q+reg (m = position).
        float* __restrict__ op = out + (size_t)(pblk + pt * 16) * 128;
#pragma unroll
        for (int reg = 0; reg < 4; ++reg)
            op[(size_t)(4 * q + reg) * 128 + 16 * w + r] = C[reg];
    }

    // ---- Stage chunk 1 into fsh[1] (separate buffer: no pre-barrier) ------
#pragma unroll
    for (int it = 0; it < 4; ++it) {
        const int g = tid + NTHR * it;
        const int p = g >> 5;
        const int i = g & 31;
        const float4 v = v1[it];
        const float a0 = v.x * v.x + v.y * v.y;
        const float a1 = v.z * v.z + v.w * v.w;
        *(f16x2*)&fsh[1][p][2 * i] =
            f16x2{ (_Float16)(a0 * v.x), (_Float16)(a1 * v.z) };
        *(f16x2*)&fsh[1][p][64 + 2 * i] =
            f16x2{ (_Float16)(a0 * v.y), (_Float16)(a1 * v.w) };
    }
    __syncthreads();

    // ---- Compute chunk 1 ---------------------------------------------------
#pragma unroll
    for (int pt = 0; pt < 4; ++pt) {
        const int pr = pt * 16 + r;
        f16x8 A0 = *(const f16x8*)&fsh[1][pr][ 0 + 8 * q];
        f16x8 A1 = *(const f16x8*)&fsh[1][pr][32 + 8 * q];
        f16x8 A2 = *(const f16x8*)&fsh[1][pr][64 + 8 * q];
        f16x8 A3 = *(const f16x8*)&fsh[1][pr][96 + 8 * q];

        floatx4 C = {0.f, 0.f, 0.f, 0.f};
        C = __builtin_amdgcn_mfma_f32_16x16x32_f16(A0, B0, C, 0, 0, 0);
        C = __builtin_amdgcn_mfma_f32_16x16x32_f16(A1, B1, C, 0, 0, 0);
        C = __builtin_amdgcn_mfma_f32_16x16x32_f16(A2, B2, C, 0, 0, 0);
        C = __builtin_amdgcn_mfma_f32_16x16x32_f16(A3, B3, C, 0, 0, 0);

        float* __restrict__ op =
            out + (size_t)(pblk + CPOS + pt * 16) * 128;
#pragma unroll
        for (int reg = 0; reg < 4; ++reg)
            op[(size_t)(4 * q + reg) * 128 + 16 * w + r] = C[reg];
    }
}

extern "C" void kernel_launch(void* const* d_in, const int* in_sizes, int n_in,
                              void* d_out, int out_size, void* d_ws, size_t ws_size,
                              hipStream_t stream) {
    const float* x = (const float*)d_in[0];   // [4,8192,64,2] fp32
    const float* W = (const float*)d_in[1];   // [64,2,126]    fp32
    float* out = (float*)d_out;               // [4,8192,64,2] fp32

    hipLaunchKernelGGL(leakage_kernel_pipe, dim3(NBLK), dim3(NTHR), 0, stream,
                       x, W, out);
}